// Round 5
// baseline (227.088 us; speedup 1.0000x reference)
//
#include <hip/hip_runtime.h>
#include <hip/hip_bf16.h>

#define DIM 1024
#define NH 16
#define HD 64
#define BB 2
#define SS 2048
#define MROWS (BB * SS)   // 4096
#define SC_LOG2E 0.04508422002778011f  // (1024^-0.5) * log2(e), folded into Q

typedef unsigned short u16;
typedef unsigned int u32;
typedef __attribute__((ext_vector_type(8))) short short8;
typedef __attribute__((ext_vector_type(4))) float f32x4;

__device__ __forceinline__ u16 f2bf(float f) {
  union { float f; u32 u; } v; v.f = f;
  return (u16)((v.u + 0x7fffu + ((v.u >> 16) & 1u)) >> 16);
}

__device__ __forceinline__ u32 pack2bf(float a, float b) {
  union { __hip_bfloat162 h; u32 u; } cv;
  cv.h = __float22bfloat162_rn(make_float2(a, b));
  return cv.u;
}

__device__ __forceinline__ void async16(const u16* g, u16* l) {
  __builtin_amdgcn_global_load_lds(
      (const __attribute__((address_space(1))) void*)(const void*)g,
      (__attribute__((address_space(3))) void*)(void*)l, 16, 0, 0);
}

__device__ __forceinline__ short8 ld8(const u16* p) { return *(const short8*)p; }

// ---------------- fp32 -> bf16 convert (vectorized) ----------------
__global__ void cvt_kernel(const float* __restrict__ in, u16* __restrict__ out, int n4) {
  int i = blockIdx.x * blockDim.x + threadIdx.x;
  if (i < n4) {
    float4 v = ((const float4*)in)[i];
    u32 lo = (u32)f2bf(v.x) | ((u32)f2bf(v.y) << 16);
    u32 hi = (u32)f2bf(v.z) | ((u32)f2bf(v.w) << 16);
    ((uint2*)out)[i] = make_uint2(lo, hi);
  }
}

// ------- transpose + convert: in fp32 [R][C] -> out bf16 [C][R] -------
__global__ void tconv_kernel(const float* __restrict__ in, u16* __restrict__ out, int R, int C) {
  __shared__ u16 t[64 * 65];
  int c0 = blockIdx.x * 64, r0 = blockIdx.y * 64;
  #pragma unroll
  for (int i = 0; i < 16; i++) {
    int j = i * 256 + threadIdx.x;
    int rr = j >> 6, cc = j & 63;
    t[rr * 65 + cc] = f2bf(in[(size_t)(r0 + rr) * C + c0 + cc]);
  }
  __syncthreads();
  #pragma unroll
  for (int i = 0; i < 16; i++) {
    int j = i * 256 + threadIdx.x;
    int oc = j >> 6, orr = j & 63;
    out[(size_t)(c0 + oc) * R + r0 + orr] = t[orr * 65 + oc];
  }
}

// ------- bf16 GEMM, m97 structure: C[M,N] = A[M,K] @ Bt[N,K]^T + bias -------
// MODE 0: QKV gemm. Writes Q/K/V in PRE-FRAGMENTED MFMA layouts (1KB frags,
//   lane-slot l*16B): qF/kF = [bh][row16][kd] (B/A-frag identical formula),
//   vF = [bh][s32][d16] B-frags. Q pre-scaled by SC_LOG2E.
// MODE 1: plain fp32 output [M][N].
template <int MODE>
__global__ __launch_bounds__(256, 2) void gemm_bt(
    const u16* __restrict__ A, const u16* __restrict__ Bt,
    const float* __restrict__ bias, void* __restrict__ C,
    u16* __restrict__ kF, u16* __restrict__ vF, int M, int N, int K) {
  __shared__ __align__(16) u16 As[128 * 32];
  __shared__ __align__(16) u16 Bs[128 * 32];
  const int tid = threadIdx.x;
  const int w = tid >> 6, l = tid & 63;
  const int r = l & 15, qd = l >> 4;
  const int m0 = blockIdx.y * 128, n0 = blockIdx.x * 128;
  const int qm = (w & 1) * 64, qn = (w >> 1) * 64;

  const size_t aoff = (size_t)(m0 + w * 16 + (l >> 2)) * K + (size_t)(l & 3) * 8;
  const size_t boff = (size_t)(n0 + w * 16 + (l >> 2)) * K + (size_t)(l & 3) * 8;
  u16* alds = &As[(w * 64 + l) * 8];
  u16* blds = &Bs[(w * 64 + l) * 8];

  f32x4 acc[4][4] = {};
  for (int k0 = 0; k0 < K; k0 += 32) {
    async16(A + aoff + k0, alds);
    async16(A + aoff + (size_t)64 * K + k0, alds + 2048);
    async16(Bt + boff + k0, blds);
    async16(Bt + boff + (size_t)64 * K + k0, blds + 2048);
    __syncthreads();
    short8 af[4], bfr[4];
    #pragma unroll
    for (int i = 0; i < 4; i++) af[i] = ld8(&As[(qm + i * 16 + r) * 32 + qd * 8]);
    #pragma unroll
    for (int j = 0; j < 4; j++) bfr[j] = ld8(&Bs[(qn + j * 16 + r) * 32 + qd * 8]);
    #pragma unroll
    for (int i = 0; i < 4; i++)
      #pragma unroll
      for (int j = 0; j < 4; j++)
        acc[i][j] = __builtin_amdgcn_mfma_f32_16x16x32_bf16(af[i], bfr[j], acc[i][j], 0, 0, 0);
    __syncthreads();
  }
  // epilogue: C layout col = lane&15, row = quad*4 + reg
  #pragma unroll
  for (int i = 0; i < 4; i++) {
    int ro = m0 + qm + i * 16 + qd * 4;
    #pragma unroll
    for (int j = 0; j < 4; j++) {
      int cb = n0 + qn + j * 16;           // 16-aligned, wave-uniform
      float bv = bias[cb + r];
      float v0 = acc[i][j][0] + bv, v1 = acc[i][j][1] + bv;
      float v2 = acc[i][j][2] + bv, v3 = acc[i][j][3] + bv;
      if (MODE == 1) {
        float* out = (float*)C;
        int col = cb + r;
        out[(size_t)(ro + 0) * N + col] = v0;
        out[(size_t)(ro + 1) * N + col] = v1;
        out[(size_t)(ro + 2) * N + col] = v2;
        out[(size_t)(ro + 3) * N + col] = v3;
      } else {
        int h = cb / 192, wib = cb - h * 192;   // uniform per j (16-col groups never cross q/k/v bounds)
        int bb = ro >> 11, s = ro & 2047;
        int bh = bb * 16 + h;
        if (wib < 128) {
          // Q or K -> fragment layout (identical formula, different base)
          int d = (wib & 63) + r;
          u16* dst = (wib < 64) ? (u16*)C : kF;
          if (wib < 64) { v0 *= SC_LOG2E; v1 *= SC_LOG2E; v2 *= SC_LOG2E; v3 *= SC_LOG2E; }
          size_t fr = ((size_t)bh * 128 + (s >> 4)) * 2 + (d >> 5);
          size_t bo = fr * 512 + (size_t)((d & 31) >> 3) * 128 + (d & 7) + (size_t)qd * 32;
          dst[bo + 0]  = f2bf(v0);
          dst[bo + 8]  = f2bf(v1);
          dst[bo + 16] = f2bf(v2);
          dst[bo + 24] = f2bf(v3);
        } else {
          // V -> B-fragment layout, packed uint2 store
          int d = (wib - 128) + r;
          size_t fr = ((size_t)bh * 64 + (s >> 5)) * 4 + (d >> 4);
          int lb = r + 16 * ((i & 1) * 2 + (qd >> 1));
          uint2 pk = make_uint2(pack2bf(v0, v1), pack2bf(v2, v3));
          *(uint2*)&vF[fr * 512 + (size_t)lb * 8 + (qd & 1) * 4] = pk;
        }
      }
    }
  }
}

// ---------------- zero init for atomic accumulators ----------------
__global__ void zero_kernel(float4* __restrict__ po4, float4* __restrict__ dl4) {
  int i = blockIdx.x * 256 + threadIdx.x;
  float4 z = {0.f, 0.f, 0.f, 0.f};
  if (i < (MROWS * NH * HD / 4)) po4[i] = z;   // 16 MB / 16
  if (i < (MROWS * NH / 4)) dl4[i] = z;
}

// ------------------------- fused attention v5 -------------------------
// Block = (b,h, 128 q-rows, kv-half). 4 waves x 32q. Everything in MFMA
// fragment layout: staging = contiguous async16, all ds_read_b128 are
// lane-slot reads (conflict-free). P round-trips wave-private frag LDS.
// kv-split x2: partial O,l accumulate via fp32 atomicAdd (no max-sub, so
// partials are linear). LDS = 40960 B -> 4 blocks/CU.
__global__ __launch_bounds__(256, 3) void attn5_kernel(
    const u16* __restrict__ qF, const u16* __restrict__ kF,
    const u16* __restrict__ vF, float* __restrict__ po,
    float* __restrict__ dl) {
  __shared__ __align__(16) u16 Ks[16 * 512];   // 16 K-frags (8 s16 x 2 kd)
  __shared__ __align__(16) u16 Vs[16 * 512];   // 16 V-frags (4 s32 x 4 dj)
  __shared__ __align__(16) u16 Ps[4][2 * 512]; // per-wave 2 P-frags
  const int tid = threadIdx.x;
  const int w = tid >> 6, l = tid & 63;
  const int r = l & 15, qd = l >> 4;
  const int half = blockIdx.x & 1, qblk = blockIdx.x >> 1;
  const int bh = blockIdx.z * NH + blockIdx.y;
  const int q0 = qblk * 128;

  const u16* qFb = qF + (size_t)bh * 128 * 2 * 512;
  const u16* kFb = kF + (size_t)bh * 128 * 2 * 512;
  const u16* vFb = vF + (size_t)bh * 64 * 4 * 512;
  u16* pw = &Ps[w][0];
  const int pwo = r * 8 + (qd >> 1) * 128 + (qd & 1) * 4;  // P-write lane offset

  short8 qf[2][2];
  #pragma unroll
  for (int i = 0; i < 2; i++)
    #pragma unroll
    for (int kd = 0; kd < 2; kd++)
      qf[i][kd] = ld8(qFb + ((size_t)((q0 >> 4) + w * 2 + i) * 2 + kd) * 512 + l * 8);

  short8 ones;
  #pragma unroll
  for (int e = 0; e < 8; e++) ones[e] = (short)0x3F80;  // bf16 1.0

  f32x4 oacc[2][4] = {};
  f32x4 dacc[2] = {};

  const int kvend = half * 1024 + 1024;
  for (int kv0 = half * 1024; kv0 < kvend; kv0 += 128) {
    // stage 16 K-frags + 16 V-frags (contiguous in frag space), 8 async16/wave
    const u16* ksrc = kFb + (size_t)(kv0 >> 4) * 2 * 512;
    const u16* vsrc = vFb + (size_t)(kv0 >> 5) * 4 * 512;
    #pragma unroll
    for (int t = 0; t < 4; t++) {
      int fi = w * 4 + t;
      async16(ksrc + fi * 512 + l * 8, &Ks[fi * 512 + l * 8]);
      async16(vsrc + fi * 512 + l * 8, &Vs[fi * 512 + l * 8]);
    }
    __syncthreads();

    #pragma unroll
    for (int ks = 0; ks < 4; ks++) {
      // S^T = K Q^T for 32 kv-rows: frag fi = ks*4 + j*2 + kd
      short8 a00 = ld8(&Ks[(ks * 4 + 0) * 512 + l * 8]);
      short8 a01 = ld8(&Ks[(ks * 4 + 1) * 512 + l * 8]);
      short8 a10 = ld8(&Ks[(ks * 4 + 2) * 512 + l * 8]);
      short8 a11 = ld8(&Ks[(ks * 4 + 3) * 512 + l * 8]);
      f32x4 s00 = {}, s01 = {}, s10 = {}, s11 = {};
      s00 = __builtin_amdgcn_mfma_f32_16x16x32_bf16(a00, qf[0][0], s00, 0, 0, 0);
      s00 = __builtin_amdgcn_mfma_f32_16x16x32_bf16(a01, qf[0][1], s00, 0, 0, 0);
      s01 = __builtin_amdgcn_mfma_f32_16x16x32_bf16(a00, qf[1][0], s01, 0, 0, 0);
      s01 = __builtin_amdgcn_mfma_f32_16x16x32_bf16(a01, qf[1][1], s01, 0, 0, 0);
      s10 = __builtin_amdgcn_mfma_f32_16x16x32_bf16(a10, qf[0][0], s10, 0, 0, 0);
      s10 = __builtin_amdgcn_mfma_f32_16x16x32_bf16(a11, qf[0][1], s10, 0, 0, 0);
      s11 = __builtin_amdgcn_mfma_f32_16x16x32_bf16(a10, qf[1][0], s11, 0, 0, 0);
      s11 = __builtin_amdgcn_mfma_f32_16x16x32_bf16(a11, qf[1][1], s11, 0, 0, 0);
      // P = exp2(S) -> wave-private P-frags (A-layout), packed uint2 writes
      {
        uint2 pk;
        pk = make_uint2(pack2bf(__builtin_exp2f(s00[0]), __builtin_exp2f(s00[1])),
                        pack2bf(__builtin_exp2f(s00[2]), __builtin_exp2f(s00[3])));
        *(uint2*)&pw[0 * 512 + pwo + 0 * 256] = pk;      // j=0, i=0
        pk = make_uint2(pack2bf(__builtin_exp2f(s01[0]), __builtin_exp2f(s01[1])),
                        pack2bf(__builtin_exp2f(s01[2]), __builtin_exp2f(s01[3])));
        *(uint2*)&pw[1 * 512 + pwo + 0 * 256] = pk;      // j=0, i=1
        pk = make_uint2(pack2bf(__builtin_exp2f(s10[0]), __builtin_exp2f(s10[1])),
                        pack2bf(__builtin_exp2f(s10[2]), __builtin_exp2f(s10[3])));
        *(uint2*)&pw[0 * 512 + pwo + 1 * 256] = pk;      // j=1, i=0
        pk = make_uint2(pack2bf(__builtin_exp2f(s11[0]), __builtin_exp2f(s11[1])),
                        pack2bf(__builtin_exp2f(s11[2]), __builtin_exp2f(s11[3])));
        *(uint2*)&pw[1 * 512 + pwo + 1 * 256] = pk;      // j=1, i=1
      }
      short8 pa0 = ld8(&pw[0 * 512 + l * 8]);
      short8 pa1 = ld8(&pw[1 * 512 + l * 8]);
      dacc[0] = __builtin_amdgcn_mfma_f32_16x16x32_bf16(pa0, ones, dacc[0], 0, 0, 0);
      dacc[1] = __builtin_amdgcn_mfma_f32_16x16x32_bf16(pa1, ones, dacc[1], 0, 0, 0);
      #pragma unroll
      for (int dj = 0; dj < 4; dj++) {
        short8 vb = ld8(&Vs[(ks * 4 + dj) * 512 + l * 8]);
        oacc[0][dj] = __builtin_amdgcn_mfma_f32_16x16x32_bf16(pa0, vb, oacc[0][dj], 0, 0, 0);
        oacc[1][dj] = __builtin_amdgcn_mfma_f32_16x16x32_bf16(pa1, vb, oacc[1][dj], 0, 0, 0);
      }
    }
    __syncthreads();
  }
  // accumulate partials (kv-halves) via atomics; O rows in C-layout
  #pragma unroll
  for (int i = 0; i < 2; i++)
    #pragma unroll
    for (int e = 0; e < 4; e++) {
      int row = q0 + w * 32 + i * 16 + qd * 4 + e;
      float* pr = po + ((size_t)bh * SS + row) * HD;
      #pragma unroll
      for (int dj = 0; dj < 4; dj++)
        atomicAdd(pr + dj * 16 + r, oacc[i][dj][e]);
      if (r == 0) atomicAdd(dl + (size_t)bh * SS + row, dacc[i][e]);
    }
}

// ---------------- normalize + relayout to attno [b][s][h*64+d] ----------------
__global__ void reduce_kernel(const float* __restrict__ po, const float* __restrict__ dl,
                              u16* __restrict__ attno) {
  int i = blockIdx.x * 256 + threadIdx.x;     // over MROWS*NH*HD/4 = 1048576
  int row = i >> 4, dg = i & 15;              // row = bh*2048 + s
  int bh = row >> 11, s = row & 2047;
  int b = bh >> 4, h = bh & 15;
  float4 o = ((const float4*)po)[i];
  float inv = 1.f / dl[row];
  uint2 pk = make_uint2(pack2bf(o.x * inv, o.y * inv), pack2bf(o.z * inv, o.w * inv));
  *(uint2*)&attno[(size_t)(b * SS + s) * DIM + h * HD + dg * 4] = pk;
}

extern "C" void kernel_launch(void* const* d_in, const int* in_sizes, int n_in,
                              void* d_out, int out_size, void* d_ws, size_t ws_size,
                              hipStream_t stream) {
  const float* x      = (const float*)d_in[0];
  const float* w_qkv  = (const float*)d_in[1];
  const float* b_qkv  = (const float*)d_in[2];
  const float* w_proj = (const float*)d_in[3];
  const float* b_proj = (const float*)d_in[4];
  float* out = (float*)d_out;
  char* ws = (char*)d_ws;
  // workspace layout (48 MB)
  u16* qF     = (u16*)(ws);                       // [32][128][2] frags   8 MB
  u16* kF     = (u16*)(ws + ((size_t)8  << 20));  // [32][128][2] frags   8 MB
  u16* vF     = (u16*)(ws + ((size_t)16 << 20));  // [32][64][4] frags    8 MB
  u16* wprojT = (u16*)(ws + ((size_t)24 << 20));  // [1024,1024]          2 MB
  u16* attno  = (u16*)(ws + ((size_t)26 << 20));  // [4096,1024]          8 MB
  u16* xb     = (u16*)(ws + ((size_t)34 << 20));  // [4096,1024]          8 MB (dead after gemm0)
  u16* wqkvT  = (u16*)(ws + ((size_t)42 << 20));  // [3072,1024]          6 MB (dead after gemm0)
  float* dl   = (float*)(ws + ((size_t)34 << 20));// 256 KB, overlays dead xb
  float* po   = out;                               // 16 MB scratch in d_out, overwritten by gemm1

  cvt_kernel<<<4096, 256, 0, stream>>>(x, xb, MROWS * DIM / 4);
  tconv_kernel<<<dim3(48, 16), 256, 0, stream>>>(w_qkv, wqkvT, DIM, 3 * DIM);
  tconv_kernel<<<dim3(16, 16), 256, 0, stream>>>(w_proj, wprojT, DIM, DIM);
  gemm_bt<0><<<dim3(24, 32), 256, 0, stream>>>(xb, wqkvT, b_qkv, qF, kF, vF, MROWS, 3 * DIM, DIM);
  zero_kernel<<<4096, 256, 0, stream>>>((float4*)po, (float4*)dl);
  attn5_kernel<<<dim3(32, NH, BB), 256, 0, stream>>>(qF, kF, vF, po, dl);
  reduce_kernel<<<4096, 256, 0, stream>>>(po, dl, attno);
  gemm_bt<1><<<dim3(8, 32), 256, 0, stream>>>(attno, wprojT, b_proj, out, nullptr, nullptr, MROWS, DIM, DIM);
}